// Round 9
// baseline (419.073 us; speedup 1.0000x reference)
//
#include <hip/hip_runtime.h>
#include <stdint.h>

#define N_K   10000
#define CIN   3
#define SEQ   1000
#define KM    11
#define NCLS  1024   // class key = (d-1)*4 + padbits ; d <= 166 -> key < 668
#define MAXQ  3400   // >= 10000/4 + NCLS

typedef _Float16 h2 __attribute__((ext_vector_type(2)));

// ---- workspace layout (int units) ------------------------------------------
// [b*16] for b in 0..15: per-batch queue counters (one cacheline each)
// [256]: Qtot
#define WS_QUADS_OFF   320
#define WS_SORT_OFF    (WS_QUADS_OFF + 2*(MAXQ+2))
#define WS_QDIL_OFF    (WS_SORT_OFF + N_K)
#define WS_QSPAN_OFF   (WS_QDIL_OFF + MAXQ + 4)
#define WS_QMETA_OFF   (WS_QSPAN_OFF + 2*(MAXQ+2))
#define WS_QBIAS_OFF   (WS_QMETA_OFF + 4*(MAXQ+2))
#define WS_QJ_OFF      (WS_QBIAS_OFF + 4*(MAXQ+2))
#define WS_QW_OFF      (WS_QJ_OFF + 4*(MAXQ+2))     // 68 u32 per quad

// ---------------- build: class-sort + quad emission + pack (1 block) ---------
__global__ __launch_bounds__(1024) void build_kernel(
    const float* __restrict__ w, const float* __restrict__ bias,
    const int* __restrict__ dil, const int* __restrict__ start,
    const int* __restrict__ out_len, const int* __restrict__ pad_max_p,
    int* __restrict__ ws) {
  __shared__ int sA[NCLS];
  __shared__ int sB[NCLS];
  const int tid = threadIdx.x;
  const int pm = pad_max_p[0];

  int2* quads  = (int2*)(ws + WS_QUADS_OFF);
  int* sortedj = ws + WS_SORT_OFF;

  // 1. class histogram
  sA[tid] = 0;
  __syncthreads();
  for (int j = tid; j < N_K; j += 1024) {
    int d = dil[j];
    int pads = pm - start[j];
    int key = (d - 1) * 4 + (pads > 0 ? 2 : 0) + (2 * pads > 7 * d ? 1 : 0);
    atomicAdd(&sA[min(key, NCLS - 1)], 1);
  }
  __syncthreads();
  // 2. inclusive scan (hazard-free)
  for (int off = 1; off < NCLS; off <<= 1) {
    int v = (tid >= off) ? sA[tid - off] : 0;
    __syncthreads();
    sA[tid] += v;
    __syncthreads();
  }
  sB[tid] = tid ? sA[tid - 1] : 0;
  __syncthreads();
  // 3. scatter j -> sortedj (class-grouped)
  for (int j = tid; j < N_K; j += 1024) {
    int d = dil[j];
    int pads = pm - start[j];
    int key = (d - 1) * 4 + (pads > 0 ? 2 : 0) + (2 * pads > 7 * d ? 1 : 0);
    int pos = atomicAdd(&sB[min(key, NCLS - 1)], 1);
    sortedj[pos] = j;
  }
  __syncthreads();
  // 4. per-class quad counts -> scan -> emit quads
  const int n_c = sA[tid] - (tid ? sA[tid - 1] : 0);
  const int cstart = sA[tid] - n_c;
  const int nq_c = (n_c + 3) >> 2;
  sB[tid] = nq_c;
  __syncthreads();
  for (int off = 1; off < NCLS; off <<= 1) {
    int v = (tid >= off) ? sB[tid - off] : 0;
    __syncthreads();
    sB[tid] += v;
    __syncthreads();
  }
  const int qstart = sB[tid] - nq_c;
  for (int u = 0; u < nq_c; ++u)
    quads[qstart + u] = make_int2(cstart + 4 * u, cstart + n_c - 1);
  __syncthreads();
  const int Qtot = sB[NCLS - 1];
  if (tid == 0) {
    ws[256] = Qtot;
    for (int i = 0; i < 16; ++i) ws[i * 16] = 0;  // padded queue counters
  }
  __syncthreads();

  // 5. pack per-(quad,member): meta + fp16 weights
  int* qdil = ws + WS_QDIL_OFF;
  int2* qspan = (int2*)(ws + WS_QSPAN_OFF);
  int* qmeta = ws + WS_QMETA_OFF;
  float* qbias = (float*)(ws + WS_QBIAS_OFF);
  int* qjv = ws + WS_QJ_OFF;
  unsigned* qw = (unsigned*)(ws + WS_QW_OFF);

  for (int g = tid; g < Qtot * 4; g += 1024) {
    const int q = g >> 2;
    const int m = g & 3;
    const int2 qr = quads[q];
    const int jm = sortedj[min(qr.x + m, qr.y)];

    const int smv = start[jm];
    const int ol = out_len[jm];
    qmeta[4 * q + m] = (smv << 16) | ol;
    qbias[4 * q + m] = bias[jm];
    qjv[4 * q + m] = jm;

    if (m == 0) {
      qdil[q] = dil[jm];
      int tlo = 0x7fffffff, thi = 0;
#pragma unroll
      for (int mm = 0; mm < 4; ++mm) {
        int jx = sortedj[min(qr.x + mm, qr.y)];
        int s2 = start[jx], o2 = out_len[jx];
        tlo = min(tlo, s2);
        thi = max(thi, s2 + o2);
      }
      qspan[q] = make_int2(tlo, thi);
    }

    // W[m*11+k] = (w_c0,w_c1); W[44+m*6+kp] = (w_c2[2kp], w_c2[2kp+1]), kp=5 pad 0
    const float* wj = w + (size_t)jm * (CIN * KM);
    unsigned* qq = qw + (size_t)q * 68;
#pragma unroll
    for (int k = 0; k < KM; ++k) {
      h2 a;
      a.x = (_Float16)wj[k];
      a.y = (_Float16)wj[KM + k];
      qq[m * KM + k] = __builtin_bit_cast(unsigned, a);
    }
    const float* w2 = wj + 2 * KM;
#pragma unroll
    for (int kp = 0; kp < 6; ++kp) {
      h2 a;
      a.x = (_Float16)w2[2 * kp];
      a.y = (kp < 5) ? (_Float16)w2[2 * kp + 1] : (_Float16)0.f;
      qq[44 + m * 6 + kp] = __builtin_bit_cast(unsigned, a);
    }
  }
}

// ---------------- main -------------------------------------------------------
// block = 4 waves; wave <-> one batch. Wave = 2 quad-groups x 32 consecutive
// tau-lanes; tau-loop unrolled x2 (lane handles tau and tau+32) -> 22
// independent ds_read_b64 in flight per iteration (in-wave MLP; R8 showed
// latency, not pipes, is the limiter). Stride-1 b64 = zero conflicts
// (R4/R6/R7/R8). Weights per-lane in VGPRs (caps/SGPR plans spill: R4/R6).
__global__ __launch_bounds__(256) void rocket_kernel(
    const float* __restrict__ x, const int* __restrict__ pad_max_p,
    int* __restrict__ ws, float* __restrict__ out) {
  __shared__ __align__(16) unsigned long long xs[4 * 1002];

  const int tid = threadIdx.x;
  const int wv = tid >> 6;          // wave = batch within group
  const int lane = tid & 63;
  const int g = lane >> 5;          // quad-group within pair
  const int s = lane & 31;          // tau slot (consecutive)
  const int bg = blockIdx.x & 3;    // 4 batch groups of 4
  const int b = bg * 4 + wv;

  // stage 4 batches, packed (c0,c1|c2,0) fp16 per position; sentinels 0/1001
  for (int lbb = 0; lbb < 4; ++lbb) {
    const float* xb = x + (size_t)(bg * 4 + lbb) * (CIN * SEQ);
    for (int pos = tid; pos < SEQ; pos += 256) {
      float a0 = xb[pos];
      float a1 = xb[SEQ + pos];
      float a2 = xb[2 * SEQ + pos];
      unsigned u0 = (unsigned)__builtin_bit_cast(unsigned short, (_Float16)a0);
      unsigned u1 = (unsigned)__builtin_bit_cast(unsigned short, (_Float16)a1);
      unsigned u2 = (unsigned)__builtin_bit_cast(unsigned short, (_Float16)a2);
      xs[lbb * 1002 + 1 + pos] =
          (unsigned long long)(u0 | (u1 << 16)) | ((unsigned long long)u2 << 32);
    }
  }
  if (tid < 8) xs[(tid >> 1) * 1002 + (tid & 1) * 1001] = 0ULL;
  __syncthreads();

  const int pm = pad_max_p[0];
  const int Q = __builtin_amdgcn_readfirstlane(ws[256]);
  const int NP = (Q + 1) >> 1;
  int* ctr = ws;
  const int* qdil = ws + WS_QDIL_OFF;
  const int2* qspan = (const int2*)(ws + WS_QSPAN_OFF);
  const int4* qmeta = (const int4*)(ws + WS_QMETA_OFF);
  const float4* qbias = (const float4*)(ws + WS_QBIAS_OFF);
  const int4* qjv = (const int4*)(ws + WS_QJ_OFF);
  const unsigned* qw = (const unsigned*)(ws + WS_QW_OFF);

  const unsigned long long* xbase = xs + wv * 1002;

  for (int pull = 0; pull <= NP; ++pull) {
    int o = 0;
    if (lane == 0) o = atomicAdd(&ctr[b * 16], 1);
    o = __builtin_amdgcn_readfirstlane(o);
    if (o >= NP) break;
    const int q = min(2 * o + g, Q - 1);

    const int d = qdil[q];
    const int2 spanq = qspan[q];
    const int4 meta = qmeta[q];
    const float4 bv = qbias[q];
    const int4 jv = qjv[q];

    unsigned W[68];
    {
      const uint4* wp = (const uint4*)(qw + (size_t)q * 68);
#pragma unroll
      for (int i = 0; i < 17; ++i) {
        uint4 u = wp[i];
        W[4 * i + 0] = u.x;
        W[4 * i + 1] = u.y;
        W[4 * i + 2] = u.z;
        W[4 * i + 3] = u.w;
      }
    }
    int sm[4], olm[4];
    float bb[4], nb[4];
    {
      const int* mp = (const int*)&meta;
      const float* bp2 = (const float*)&bv;
#pragma unroll
      for (int m = 0; m < 4; ++m) {
        sm[m] = mp[m] >> 16;
        olm[m] = mp[m] & 0xffff;
        bb[m] = bp2[m];
        nb[m] = -bb[m];
      }
    }

    // pair-uniform tau range (union of the two quads' spans)
    int t0 = min(spanq.x, __shfl_xor(spanq.x, 32));
    int t1 = max(spanq.y, __shfl_xor(spanq.y, 32));
    t0 = __builtin_amdgcn_readfirstlane(t0);
    t1 = __builtin_amdgcn_readfirstlane(t1);
    const int nIter = (t1 - t0 + 63) >> 6;   // 64 tau per lane per iter (2x32)

    int t = t0 + s;
    int pb = 1 + t - pm;  // LDS slot of tap 0 for chunk A (slot = 1 + position)

    float mx[4] = {-3.0e38f, -3.0e38f, -3.0e38f, -3.0e38f};
    int cnt[4] = {0, 0, 0, 0};

#pragma unroll 1
    for (int i = 0; i < nIter; ++i) {
      // ---- issue all 22 loads (2 tau-chunks x 11 taps), independent --------
      unsigned long long va[KM], vb[KM];
      int addr = pb;
#pragma unroll
      for (int k = 0; k < KM; ++k) {
        int aa = min(max(addr, 0), 1001);
        int ab = min(max(addr + 32, 0), 1001);
        va[k] = xbase[aa];
        vb[k] = xbase[ab];
        addr += d;
      }
      // ---- chunk A (tau = t) ----------------------------------------------
      {
        float a0[4] = {0.f, 0.f, 0.f, 0.f};
        float a1[4] = {0.f, 0.f, 0.f, 0.f};
#pragma unroll
        for (int kp = 0; kp < 5; ++kp) {
          unsigned loA = (unsigned)va[2 * kp], hiA = (unsigned)(va[2 * kp] >> 32);
          unsigned loB = (unsigned)va[2 * kp + 1], hiB = (unsigned)(va[2 * kp + 1] >> 32);
          h2 xA = __builtin_bit_cast(h2, loA);
          h2 xB = __builtin_bit_cast(h2, loB);
          h2 xP = __builtin_bit_cast(h2,
                    __builtin_amdgcn_perm(hiB, hiA, 0x05040100u));
#pragma unroll
          for (int m = 0; m < 4; ++m) {
            a0[m] = __builtin_amdgcn_fdot2(xA, __builtin_bit_cast(h2, W[m * KM + 2 * kp]), a0[m], false);
            a0[m] = __builtin_amdgcn_fdot2(xB, __builtin_bit_cast(h2, W[m * KM + 2 * kp + 1]), a0[m], false);
            a1[m] = __builtin_amdgcn_fdot2(xP, __builtin_bit_cast(h2, W[44 + m * 6 + kp]), a1[m], false);
          }
        }
        {
          unsigned loL = (unsigned)va[10], hiL = (unsigned)(va[10] >> 32);
          h2 xL = __builtin_bit_cast(h2, loL);
          h2 xH = __builtin_bit_cast(h2, hiL);
#pragma unroll
          for (int m = 0; m < 4; ++m) {
            a0[m] = __builtin_amdgcn_fdot2(xL, __builtin_bit_cast(h2, W[m * KM + 10]), a0[m], false);
            a1[m] = __builtin_amdgcn_fdot2(xH, __builtin_bit_cast(h2, W[44 + m * 6 + 5]), a1[m], false);
          }
        }
#pragma unroll
        for (int m = 0; m < 4; ++m) {
          float val = a0[m] + a1[m];
          bool in = (unsigned)(t - sm[m]) < (unsigned)olm[m];
          mx[m] = fmaxf(mx[m], in ? val : -3.0e38f);
          cnt[m] += (in && val > nb[m]) ? 1 : 0;
        }
      }
      // ---- chunk B (tau = t + 32) ------------------------------------------
      {
        float a0[4] = {0.f, 0.f, 0.f, 0.f};
        float a1[4] = {0.f, 0.f, 0.f, 0.f};
#pragma unroll
        for (int kp = 0; kp < 5; ++kp) {
          unsigned loA = (unsigned)vb[2 * kp], hiA = (unsigned)(vb[2 * kp] >> 32);
          unsigned loB = (unsigned)vb[2 * kp + 1], hiB = (unsigned)(vb[2 * kp + 1] >> 32);
          h2 xA = __builtin_bit_cast(h2, loA);
          h2 xB = __builtin_bit_cast(h2, loB);
          h2 xP = __builtin_bit_cast(h2,
                    __builtin_amdgcn_perm(hiB, hiA, 0x05040100u));
#pragma unroll
          for (int m = 0; m < 4; ++m) {
            a0[m] = __builtin_amdgcn_fdot2(xA, __builtin_bit_cast(h2, W[m * KM + 2 * kp]), a0[m], false);
            a0[m] = __builtin_amdgcn_fdot2(xB, __builtin_bit_cast(h2, W[m * KM + 2 * kp + 1]), a0[m], false);
            a1[m] = __builtin_amdgcn_fdot2(xP, __builtin_bit_cast(h2, W[44 + m * 6 + kp]), a1[m], false);
          }
        }
        {
          unsigned loL = (unsigned)vb[10], hiL = (unsigned)(vb[10] >> 32);
          h2 xL = __builtin_bit_cast(h2, loL);
          h2 xH = __builtin_bit_cast(h2, hiL);
#pragma unroll
          for (int m = 0; m < 4; ++m) {
            a0[m] = __builtin_amdgcn_fdot2(xL, __builtin_bit_cast(h2, W[m * KM + 10]), a0[m], false);
            a1[m] = __builtin_amdgcn_fdot2(xH, __builtin_bit_cast(h2, W[44 + m * 6 + 5]), a1[m], false);
          }
        }
        const int t2 = t + 32;
#pragma unroll
        for (int m = 0; m < 4; ++m) {
          float val = a0[m] + a1[m];
          bool in = (unsigned)(t2 - sm[m]) < (unsigned)olm[m];
          mx[m] = fmaxf(mx[m], in ? val : -3.0e38f);
          cnt[m] += (in && val > nb[m]) ? 1 : 0;
        }
      }
      t += 64;
      pb += 64;
    }

    // reduce across the 32 tau-lanes of this quad-group
#pragma unroll
    for (int m = 0; m < 4; ++m) {
#pragma unroll
      for (int off = 1; off < 32; off <<= 1) {
        mx[m] = fmaxf(mx[m], __shfl_xor(mx[m], off));
        cnt[m] += __shfl_xor(cnt[m], off);
      }
    }
    if (s == 0) {
      const int* jp = (const int*)&jv;
#pragma unroll
      for (int m = 0; m < 4; ++m) {
        float2 r;
        r.x = mx[m] + bb[m];
        r.y = (float)cnt[m] / (float)olm[m];
        *(float2*)(out + (size_t)b * (2 * N_K) + 2 * jp[m]) = r;
      }
    }
  }
}

extern "C" void kernel_launch(void* const* d_in, const int* in_sizes, int n_in,
                              void* d_out, int out_size, void* d_ws, size_t ws_size,
                              hipStream_t stream) {
  const float* x       = (const float*)d_in[0];
  const float* weight  = (const float*)d_in[1];
  const float* bias    = (const float*)d_in[2];
  const int*   dil     = (const int*)d_in[3];
  const int*   start   = (const int*)d_in[4];
  const int*   out_len = (const int*)d_in[5];
  const int*   pad_max = (const int*)d_in[6];
  (void)in_sizes; (void)n_in; (void)out_size; (void)ws_size;

  int* ws = (int*)d_ws;

  build_kernel<<<1, 1024, 0, stream>>>(weight, bias, dil, start, out_len,
                                       pad_max, ws);
  rocket_kernel<<<1280, 256, 0, stream>>>(x, pad_max, ws, (float*)d_out);
}